// Round 4
// baseline (170.501 us; speedup 1.0000x reference)
//
#include <hip/hip_runtime.h>

#define NCLS 21
#define BLK 256

// Unaligned (4B-aligned) 16-byte global load -> global_load_dwordx4.
__device__ __forceinline__ float4 load_f4_unaligned(const float* p) {
    float4 v;
    __builtin_memcpy(&v, p, 16);
    return v;
}

__global__ __launch_bounds__(BLK) void focal_main(
    const float* __restrict__ loc_p,
    const float* __restrict__ loc_t,
    const float* __restrict__ cls_p,
    const int*   __restrict__ cls_t,
    float2* __restrict__ partials,
    int n_anchors)
{
    const int tid  = threadIdx.x;
    const int wave = tid >> 6;
    const int lane = tid & 63;
    const long long a = (long long)blockIdx.x * BLK + tid;

    float acc  = 0.0f;
    float npos = 0.0f;

    if (a < n_anchors) {
        // ---- issue all 9 VMEM up front: 1 dword + 2 dwordx4 + 6 row loads ----
        const int t = cls_t[a];
        const float4 lp = ((const float4*)loc_p)[a];
        const float4 lt = ((const float4*)loc_t)[a];

        const float* g = cls_p + a * NCLS;
        float row[NCLS];
        #pragma unroll
        for (int k = 0; k < 5; ++k) {
            float4 r = load_f4_unaligned(g + k * 4);
            row[k * 4 + 0] = r.x; row[k * 4 + 1] = r.y;
            row[k * 4 + 2] = r.z; row[k * 4 + 3] = r.w;
        }
        row[20] = g[20];

        // ---- smooth L1, masked by (t > 0) ----
        {
            float d0 = lp.x - lt.x, d1 = lp.y - lt.y, d2 = lp.z - lt.z, d3 = lp.w - lt.w;
            float a0 = fabsf(d0), a1 = fabsf(d1), a2 = fabsf(d2), a3 = fabsf(d3);
            float s = 0.0f;
            s += (a0 < 1.0f) ? 0.5f * d0 * d0 : a0 - 0.5f;
            s += (a1 < 1.0f) ? 0.5f * d1 * d1 : a1 - 0.5f;
            s += (a2 < 1.0f) ? 0.5f * d2 * d2 : a2 - 0.5f;
            s += (a3 < 1.0f) ? 0.5f * d3 * d3 : a3 - 0.5f;
            if (t > 0) { acc = s; npos = 1.0f; }
        }

        // ---- focal loss over non-ignored anchors (t >= 0), all in registers ----
        if (t >= 0) {
            float m = row[0];
            #pragma unroll
            for (int j = 1; j < NCLS; ++j) m = fmaxf(m, row[j]);
            float s = 0.0f;
            #pragma unroll
            for (int j = 0; j < NCLS; ++j) s += __expf(row[j] - m);
            float pt = __expf(row[t] - m) / s;
            pt = fminf(fmaxf(pt, 1e-7f), 1.0f - 1e-7f);
            float om = 1.0f - pt;
            acc += -__logf(pt) * om * om;
        }
    }

    // ---- per-wave reduction, one float2 store per wave, no LDS, no atomics ----
    #pragma unroll
    for (int off = 32; off > 0; off >>= 1) {
        acc  += __shfl_down(acc,  off, 64);
        npos += __shfl_down(npos, off, 64);
    }
    if (lane == 0)
        partials[blockIdx.x * 4 + wave] = make_float2(acc, npos);
}

#define RBLK 1024
__global__ __launch_bounds__(RBLK) void focal_reduce(
    const float2* __restrict__ partials, float* __restrict__ out, int npart)
{
    __shared__ float red[32];
    float L = 0.0f, P = 0.0f;
    for (int i = threadIdx.x; i < npart; i += RBLK) {
        float2 v = partials[i];
        L += v.x; P += v.y;
    }
    #pragma unroll
    for (int off = 32; off > 0; off >>= 1) {
        L += __shfl_down(L, off, 64);
        P += __shfl_down(P, off, 64);
    }
    const int wave = threadIdx.x >> 6, lane = threadIdx.x & 63;
    if (lane == 0) { red[wave * 2] = L; red[wave * 2 + 1] = P; }
    __syncthreads();
    if (threadIdx.x == 0) {
        float Ls = 0.0f, Ps = 0.0f;
        #pragma unroll
        for (int w = 0; w < RBLK / 64; ++w) { Ls += red[w * 2]; Ps += red[w * 2 + 1]; }
        out[0] = Ls / Ps;
    }
}

extern "C" void kernel_launch(void* const* d_in, const int* in_sizes, int n_in,
                              void* d_out, int out_size, void* d_ws, size_t ws_size,
                              hipStream_t stream)
{
    const float* loc_p = (const float*)d_in[0];
    const float* loc_t = (const float*)d_in[1];
    const float* cls_p = (const float*)d_in[2];
    const int*   cls_t = (const int*)d_in[3];
    // d_in[4] (pos) ignored: pos == (cls_targets > 0) exactly.
    float*  out = (float*)d_out;
    float2* ws  = (float2*)d_ws;

    const int n_anchors = in_sizes[3];                 // B*A = 1,048,576
    const int blocks = (n_anchors + BLK - 1) / BLK;    // 4096

    focal_main<<<blocks, BLK, 0, stream>>>(loc_p, loc_t, cls_p, cls_t, ws, n_anchors);
    focal_reduce<<<1, RBLK, 0, stream>>>(ws, out, blocks * 4);
}